// Round 1
// baseline (415.356 us; speedup 1.0000x reference)
//
#include <hip/hip_runtime.h>

// FlowWarp via MFMA. Per level:
//   warped = bilinear_warp(xp, +fl); x = [xc(64) | warped(64) | fl(2)] (130ch)
//   out[p][f] = sum_c x[c]*dw[c]*pw[c][f] + bias[f]
// R3: per-pixel 130x64 matvec as bf16 MFMA 16x16x32; weights prepped into
//   B-fragment order in d_ws; phase1 gather->LDS bf16, phase2 MFMA.
// R4: kernel is LATENCY-bound (MfmaUtil 1.4%, VALU 7%, HBM 15%, occ 27%).
//   Occupancy was capped at 3 blocks/CU by launch_bounds + 38.9KB LDS.
//   -> LDS down to exactly 32KB (drop fl stash: epilogue re-reads fl from
//   global broadcast; drop 144B pad -> 128B rows + XOR bank swizzle
//   off ^= (row&7)<<4 on both write and read sides). launch_bounds(256,5)
//   -> 5 blocks/CU = 20 waves/CU (was 12): ~1.6x more gather loads in
//   flight, which is the whole game for the scattered bilinear fetch.

typedef __attribute__((ext_vector_type(8))) short bf16x8;
typedef __attribute__((ext_vector_type(4))) float f32x4;

#define WS_LVL_STRIDE 17408  // 16384 frag bytes + 768 table bytes, 256-align

__device__ inline unsigned rne_bf16_bits(float f) {
  unsigned u = __builtin_bit_cast(unsigned, f);
  u += 0x7fffu + ((u >> 16) & 1u);
  return u >> 16;
}
__device__ inline int pack_bf16x2(float a, float b) {
  return (int)(rne_bf16_bits(a) | (rne_bf16_bits(b) << 16));
}

struct LevelArgs {
  const float* __restrict__ xc;
  const float* __restrict__ xp;
  const float* __restrict__ fl;
  float* __restrict__ out;
  const char* __restrict__ wsl;  // frag[16KB] + tab[768B]
  int H, W, npix, block_start;
};
struct KArgs { LevelArgs lv[6]; int total_blocks; };

struct PrepLevel {
  const float* __restrict__ dw;
  const float* __restrict__ pw;
  const float* __restrict__ bias;
  char* __restrict__ wsl;
};
struct PrepArgs { PrepLevel lv[6]; };

// ---- prep: fold dw into pw, pack B-fragments (lane l holds B[k=(l>>4)*8+j][n=l&15]) ----
__global__ void prep_kernel(PrepArgs pa) {
  const PrepLevel P = pa.lv[blockIdx.x];
  int4* __restrict__ frag = (int4*)P.wsl;
  for (int e = (int)threadIdx.x; e < 1024; e += 256) {
    const int kt = e >> 8;            // k-tile 0..3 (k = kt*32 + ...)
    const int nt = (e >> 6) & 3;      // n-tile 0..3
    const int lane = e & 63;
    const int n = nt * 16 + (lane & 15);
    const int kb = kt * 32 + ((lane >> 4) & 3) * 8;
    int v[4];
#pragma unroll
    for (int jj = 0; jj < 4; ++jj) {
      const int k0 = kb + jj * 2;
      const float w0 = P.dw[k0] * P.pw[(size_t)k0 * 64 + n];
      const float w1 = P.dw[k0 + 1] * P.pw[(size_t)(k0 + 1) * 64 + n];
      v[jj] = pack_bf16x2(w0, w1);
    }
    frag[e] = make_int4(v[0], v[1], v[2], v[3]);
  }
  float* __restrict__ tab = (float*)(P.wsl + 16384);
  if (threadIdx.x < 64) {
    const int f = (int)threadIdx.x;
    tab[f] = P.bias[f];
    tab[64 + f] = P.dw[128] * P.pw[128 * 64 + f];
    tab[128 + f] = P.dw[129] * P.pw[129 * 64 + f];
  }
}

// LDS: 256 rows x 128B (64ch bf16), XOR-swizzled so 5 blocks/CU fit exactly
// (5 * 32768 = 160KB). Swizzle: byte offset within row ^= (row&7)<<4 —
// bijective per 8-row stripe, all accesses 16B-aligned; spreads both the
// b128 writes (one column per wave otherwise) and the stride-128B b128
// reads evenly across the 32 banks (8 dwords/bank = minimum for wave64).
#define SWZ(r, o) \
  ((((unsigned)(r)) << 7) | (((unsigned)(o)) ^ ((((unsigned)(r)) & 7u) << 4)))

__global__ __launch_bounds__(256, 5) void flowwarp_mfma(KArgs ka) {
  __shared__ __align__(16) char lds_raw[256 * 128];

  const int nb = ka.total_blocks;
  const int chunk = (nb + 7) >> 3;
  const int bp = (int)blockIdx.x;
  const int b = (bp & 7) * chunk + (bp >> 3);   // XCD-slab swizzle
  if (b >= nb) return;

  int Lr = 0;
#pragma unroll
  for (int i = 1; i < 6; ++i) Lr = (b >= ka.lv[i].block_start) ? i : Lr;
  const int L = __builtin_amdgcn_readfirstlane(Lr);
  const LevelArgs A = ka.lv[L];

  const int q = (int)threadIdx.x;
  const int p0 = (b - A.block_start) * 256;
  const int W = A.W, H = A.H;

  // ================= phase 1: bilinear gather -> LDS (bf16) =================
  {
    int p = p0 + q;
    if (p > A.npix - 1) p = A.npix - 1;   // tail blocks: clamp (rows unused)
    const int x = p % W;
    const int t = p / W;
    const int y = t % H;
    const int n = t / H;

    const float fl0 = A.fl[2 * (size_t)p];
    const float fl1 = A.fl[2 * (size_t)p + 1];

    const float qy = (float)y + fl0;
    const float qx = (float)x + fl1;
    const float fy = fminf(fmaxf(floorf(qy), 0.0f), (float)(H - 2));
    const float fx = fminf(fmaxf(floorf(qx), 0.0f), (float)(W - 2));
    const int y0 = (int)fy, x0 = (int)fx;
    const float ay = fminf(fmaxf(qy - fy, 0.0f), 1.0f);
    const float ax = fminf(fmaxf(qx - fx, 0.0f), 1.0f);

    const float* __restrict__ base =
        A.xp + ((size_t)((n * H + y0) * W + x0)) * 64;
    const int W64 = W * 64;
    const float4* __restrict__ tl4 = (const float4*)base;
    const float4* __restrict__ tr4 = (const float4*)(base + 64);
    const float4* __restrict__ bl4 = (const float4*)(base + W64);
    const float4* __restrict__ br4 = (const float4*)(base + W64 + 64);

#pragma unroll 1
    for (int bq = 0; bq < 4; ++bq) {   // 4 bursts x 16 ch: full-line consume
      float4 rtl[4], rtr[4], rbl[4], rbr[4];
#pragma unroll
      for (int i = 0; i < 4; ++i) {
        rtl[i] = tl4[bq * 4 + i];
        rtr[i] = tr4[bq * 4 + i];
        rbl[i] = bl4[bq * 4 + i];
        rbr[i] = br4[bq * 4 + i];
      }
      int v[8];
#pragma unroll
      for (int i = 0; i < 4; ++i) {
        const float atl[4] = {rtl[i].x, rtl[i].y, rtl[i].z, rtl[i].w};
        const float atr[4] = {rtr[i].x, rtr[i].y, rtr[i].z, rtr[i].w};
        const float abl[4] = {rbl[i].x, rbl[i].y, rbl[i].z, rbl[i].w};
        const float abr[4] = {rbr[i].x, rbr[i].y, rbr[i].z, rbr[i].w};
        float wv[4];
#pragma unroll
        for (int j = 0; j < 4; ++j) {
          const float top = fmaf(atr[j] - atl[j], ax, atl[j]);
          const float bot = fmaf(abr[j] - abl[j], ax, abl[j]);
          wv[j] = fmaf(bot - top, ay, top);
        }
        v[i * 2] = pack_bf16x2(wv[0], wv[1]);
        v[i * 2 + 1] = pack_bf16x2(wv[2], wv[3]);
      }
      *(int4*)(lds_raw + SWZ(q, bq * 32)) = make_int4(v[0], v[1], v[2], v[3]);
      *(int4*)(lds_raw + SWZ(q, bq * 32 + 16)) =
          make_int4(v[4], v[5], v[6], v[7]);
    }
  }
  __syncthreads();

  // ================= phase 2: MFMA 64pix x 64f per wave =================
  const int lane = q & 63;
  const int w = q >> 6;
  const int m16 = lane & 15;
  const int q4l = lane >> 4;

  // B-fragments: 4 ktiles x 4 ntiles, 16B/lane each, resident in VGPRs
  const int4* __restrict__ bfr = (const int4*)A.wsl;
  bf16x8 Bf[4][4];
#pragma unroll
  for (int kt = 0; kt < 4; ++kt)
#pragma unroll
    for (int nt = 0; nt < 4; ++nt)
      Bf[kt][nt] = __builtin_bit_cast(bf16x8, bfr[(kt * 4 + nt) * 64 + lane]);

  const float* __restrict__ tab = (const float*)(A.wsl + 16384);
  float bv[4], t0v[4], t1v[4];
#pragma unroll
  for (int nt = 0; nt < 4; ++nt) {
    const int col = nt * 16 + m16;
    bv[nt] = tab[col];
    t0v[nt] = tab[64 + col];
    t1v[nt] = tab[128 + col];
  }
  const float2* __restrict__ flg = (const float2*)A.fl;

#pragma unroll 1
  for (int mt = 0; mt < 4; ++mt) {
    const int lrow = w * 64 + mt * 16;
    // fl for the 4 output rows this thread epilogues (broadcast within
    // 16-lane group; L1/L2-resident — fl is tiny)
    float2 fle[4];
#pragma unroll
    for (int i = 0; i < 4; ++i) {
      int pr = p0 + lrow + q4l * 4 + i;
      if (pr > A.npix - 1) pr = A.npix - 1;
      fle[i] = flg[pr];
    }
    // A-frags, xc (k-tiles 0,1) straight from global with cvt
    int pm = p0 + lrow + m16;
    if (pm > A.npix - 1) pm = A.npix - 1;
    const float* __restrict__ xcp = A.xc + (size_t)pm * 64 + q4l * 8;
    const float4 a0 = *(const float4*)xcp;
    const float4 a1 = *(const float4*)(xcp + 4);
    const float4 a2 = *(const float4*)(xcp + 32);
    const float4 a3 = *(const float4*)(xcp + 36);
    int av[8];
    av[0] = pack_bf16x2(a0.x, a0.y); av[1] = pack_bf16x2(a0.z, a0.w);
    av[2] = pack_bf16x2(a1.x, a1.y); av[3] = pack_bf16x2(a1.z, a1.w);
    av[4] = pack_bf16x2(a2.x, a2.y); av[5] = pack_bf16x2(a2.z, a2.w);
    av[6] = pack_bf16x2(a3.x, a3.y); av[7] = pack_bf16x2(a3.z, a3.w);
    const bf16x8 A0 = __builtin_bit_cast(bf16x8, make_int4(av[0], av[1], av[2], av[3]));
    const bf16x8 A1 = __builtin_bit_cast(bf16x8, make_int4(av[4], av[5], av[6], av[7]));
    // A-frags, warped (k-tiles 2,3) from LDS (swizzled)
    const int rr = lrow + m16;
    const bf16x8 A2 = __builtin_bit_cast(
        bf16x8, *(const int4*)(lds_raw + SWZ(rr, q4l * 16)));
    const bf16x8 A3 = __builtin_bit_cast(
        bf16x8, *(const int4*)(lds_raw + SWZ(rr, 64 + q4l * 16)));

    f32x4 acc[4] = {{0.f, 0.f, 0.f, 0.f}, {0.f, 0.f, 0.f, 0.f},
                    {0.f, 0.f, 0.f, 0.f}, {0.f, 0.f, 0.f, 0.f}};
#pragma unroll
    for (int nt = 0; nt < 4; ++nt) {
      acc[nt] = __builtin_amdgcn_mfma_f32_16x16x32_bf16(A0, Bf[0][nt], acc[nt], 0, 0, 0);
      acc[nt] = __builtin_amdgcn_mfma_f32_16x16x32_bf16(A1, Bf[1][nt], acc[nt], 0, 0, 0);
      acc[nt] = __builtin_amdgcn_mfma_f32_16x16x32_bf16(A2, Bf[2][nt], acc[nt], 0, 0, 0);
      acc[nt] = __builtin_amdgcn_mfma_f32_16x16x32_bf16(A3, Bf[3][nt], acc[nt], 0, 0, 0);
    }

    // epilogue: D row r=(lane>>4)*4+i, col=lane&15 (per n-tile). fl terms exact fp32.
#pragma unroll
    for (int i = 0; i < 4; ++i) {
      const int prow = p0 + lrow + q4l * 4 + i;
      if (prow < A.npix) {
        float* __restrict__ orow = A.out + (size_t)prow * 64 + m16;
#pragma unroll
        for (int nt = 0; nt < 4; ++nt)
          orow[nt * 16] = acc[nt][i] + bv[nt] + fle[i].x * t0v[nt] + fle[i].y * t1v[nt];
      }
    }
  }
}

extern "C" void kernel_launch(void* const* d_in, const int* in_sizes, int n_in,
                              void* d_out, int out_size, void* d_ws, size_t ws_size,
                              hipStream_t stream) {
  static const int HS[6] = {192, 96, 48, 24, 12, 6};
  static const int WS[6] = {384, 192, 96, 48, 24, 12};
  PrepArgs pa;
  KArgs ka;
  int bstart = 0;
  size_t ooff = 0;
  for (int i = 0; i < 6; ++i) {
    char* wsl = (char*)d_ws + (size_t)i * WS_LVL_STRIDE;
    pa.lv[i].dw   = (const float*)d_in[6 * i + 3];
    pa.lv[i].pw   = (const float*)d_in[6 * i + 4];
    pa.lv[i].bias = (const float*)d_in[6 * i + 5];
    pa.lv[i].wsl  = wsl;
    ka.lv[i].xc  = (const float*)d_in[6 * i + 0];
    ka.lv[i].xp  = (const float*)d_in[6 * i + 1];
    ka.lv[i].fl  = (const float*)d_in[6 * i + 2];
    ka.lv[i].out = (float*)d_out + ooff;
    ka.lv[i].wsl = wsl;
    const int npix = 4 * HS[i] * WS[i];
    ka.lv[i].H = HS[i];
    ka.lv[i].W = WS[i];
    ka.lv[i].npix = npix;
    ka.lv[i].block_start = bstart;
    bstart += (npix + 255) / 256;
    ooff += (size_t)npix * 64;
  }
  ka.total_blocks = bstart;
  prep_kernel<<<dim3(6), dim3(256), 0, stream>>>(pa);
  const int chunk = (bstart + 7) >> 3;
  flowwarp_mfma<<<dim3(chunk * 8), dim3(256), 0, stream>>>(ka);
}